// Round 7
// baseline (217.485 us; speedup 1.0000x reference)
//
#include <hip/hip_runtime.h>
#include <hip/hip_bf16.h>
#include <stdint.h>

#define B_    4
#define NQ_   2048
#define NK_   2048
#define CQ_   1024
#define CK_   768
#define H_    16
#define D_    64
#define SCALE 0.125f   // 1/sqrt(64)
#define C2    0.1803368801111204f  // SCALE * log2(e)

typedef __attribute__((ext_vector_type(8))) short bf16x8;
typedef __attribute__((ext_vector_type(4))) float f32x4;

#define MFMA16(a, b, c) __builtin_amdgcn_mfma_f32_16x16x32_bf16((a), (b), (c), 0, 0, 0)

// async global->LDS, 16B per lane; LDS dest = wave-uniform base + lane*16
#define GLL16(gp, lp)                                                                 \
    __builtin_amdgcn_global_load_lds(                                                 \
        (__attribute__((address_space(1))) uint32_t*)(uintptr_t)(gp),                 \
        (__attribute__((address_space(3))) uint32_t*)(uintptr_t)(lp), 16, 0, 0)

__device__ inline unsigned short f2bf(float f) {
    union { float f; uint32_t u; } v; v.f = f;
    uint32_t u = v.u;
    return (unsigned short)((u + 0x7fffu + ((u >> 16) & 1u)) >> 16);
}

__device__ inline uint32_t packbf2(float a, float b) {
    union { __hip_bfloat162 h; uint32_t u; } v;
    v.h = __float22bfloat162_rn(float2{a, b});
    return v.u;
}

// ------------------------------------------------------- fused LayerNorm
// rows 0..8191: query tokens (W=1024); rows 8192..16383: context (W=768)
__global__ __launch_bounds__(256) void ln_fused(const float* __restrict__ xqt,
                                                const float* __restrict__ xct,
                                                const float* __restrict__ gq,
                                                const float* __restrict__ btq,
                                                const float* __restrict__ gc,
                                                const float* __restrict__ btc,
                                                unsigned short* __restrict__ oq,
                                                unsigned short* __restrict__ oc) {
    int row = blockIdx.x;
    const float *x, *gamma, *beta;
    unsigned short* out;
    int W;
    float invW;
    if (row < 8192) {
        x = xqt + (size_t)row * 1024; gamma = gq; beta = btq;
        out = oq + (size_t)row * 1024; W = 1024; invW = 1.f / 1024.f;
    } else {
        int r = row - 8192;
        x = xct + (size_t)r * 768; gamma = gc; beta = btc;
        out = oc + (size_t)r * 768; W = 768; invW = 1.f / 768.f;
    }
    int tid = threadIdx.x;
    int col = tid * 4;
    float v0 = 0.f, v1 = 0.f, v2 = 0.f, v3 = 0.f;
    float s = 0.f, s2 = 0.f;
    bool active = (col < W);
    if (active) {
        float4 vv = *(const float4*)(x + col);
        v0 = vv.x; v1 = vv.y; v2 = vv.z; v3 = vv.w;
        s = v0 + v1 + v2 + v3;
        s2 = v0 * v0 + v1 * v1 + v2 * v2 + v3 * v3;
    }
    for (int off = 32; off >= 1; off >>= 1) {
        s += __shfl_xor(s, off);
        s2 += __shfl_xor(s2, off);
    }
    __shared__ float red[8];
    __shared__ float stat[2];
    int wid = tid >> 6, lane = tid & 63;
    if (lane == 0) { red[wid] = s; red[4 + wid] = s2; }
    __syncthreads();
    if (tid == 0) {
        float ts = red[0] + red[1] + red[2] + red[3];
        float ts2 = red[4] + red[5] + red[6] + red[7];
        float mu = ts * invW;
        float var = ts2 * invW - mu * mu;
        stat[0] = mu;
        stat[1] = rsqrtf(var + 1e-5f);
    }
    __syncthreads();
    float mu = stat[0], rstd = stat[1];
    if (active) {
        float4 g = *(const float4*)(gamma + col);
        float4 b = *(const float4*)(beta + col);
        ushort4 o;
        o.x = f2bf((v0 - mu) * rstd * g.x + b.x);
        o.y = f2bf((v1 - mu) * rstd * g.y + b.y);
        o.z = f2bf((v2 - mu) * rstd * g.z + b.z);
        o.w = f2bf((v3 - mu) * rstd * g.w + b.w);
        *(ushort4*)(out + col) = o;
    }
}

// ------------------------------------- fused weight transpose + cast (all 4)
// W* are fp32 [K][1024]; outputs bf16 [N][K]. Wk,Wv go into one [2048][768].
__global__ __launch_bounds__(256) void transpose_all(const float* __restrict__ Wq,
                                                     const float* __restrict__ Wk,
                                                     const float* __restrict__ Wv,
                                                     const float* __restrict__ Wo,
                                                     unsigned short* __restrict__ Wqt,
                                                     unsigned short* __restrict__ Wkvt,
                                                     unsigned short* __restrict__ Wot) {
    __shared__ float t[32][33];
    int blk = blockIdx.x;
    const float* src;
    unsigned short* dst;
    int K;
    if (blk < 1024)      { src = Wq; dst = Wqt; K = 1024; }
    else if (blk < 1792) { blk -= 1024; src = Wk; dst = Wkvt; K = 768; }
    else if (blk < 2560) { blk -= 1792; src = Wv; dst = Wkvt + (size_t)1024 * 768; K = 768; }
    else                 { blk -= 2560; src = Wo; dst = Wot; K = 1024; }
    int n0 = (blk & 31) * 32, k0 = (blk >> 5) * 32;
    int tx = threadIdx.x, ty = threadIdx.y;  // 32 x 8
    for (int i = 0; i < 4; i++)
        t[ty + 8 * i][tx] = src[(size_t)(k0 + ty + 8 * i) * 1024 + n0 + tx];
    __syncthreads();
    for (int i = 0; i < 4; i++)
        dst[(size_t)(n0 + ty + 8 * i) * K + k0 + tx] = f2bf(t[tx][ty + 8 * i]);
}

// ------------------------------------------------------------------- GEMM
// Y[M=8192][N] = X[M][Kd] @ Wt[N][Kd]^T + bias
// MODE 0: N=1024, bf16 out remapped [b][h][n][64]           (Q)
// MODE 2: N=1024, fp32 out plain [M][1024]                  (final O)
// MODE 3: N=2048, cols 0-1023 -> K as [b][h][n][64] (out0),
//                 cols 1024-2047 -> V as [b][h][64][nk] (out1)
// Chunked XCD swizzle keeps each XCD's blocks in an m-slab (L2-fit panels).
template <int MODE>
__global__ __launch_bounds__(256) void gemm_bt(const unsigned short* __restrict__ X,
                                               const unsigned short* __restrict__ Wt,
                                               const float* __restrict__ bias0,
                                               const float* __restrict__ bias1,
                                               void* __restrict__ out0,
                                               void* __restrict__ out1, int Kd) {
    constexpr int NB = (MODE == 3) ? 16 : 8;  // n-blocks in grid.x
    __shared__ __align__(16) unsigned short As[128 * 64];
    __shared__ __align__(16) unsigned short Bs[128 * 64];
    int tid = threadIdx.x;
    int lane = tid & 63, wid = tid >> 6;

    int lin = blockIdx.y * NB + blockIdx.x;
    int virt = (lin & 7) * (NB * 8) + (lin >> 3);  // bijective chunked map
    int m0 = (virt / NB) * 128;
    int n0 = (virt % NB) * 128;
    int wm = wid >> 1, wn = wid & 1;

    f32x4 acc[4][4];
    for (int i = 0; i < 4; i++)
        for (int j = 0; j < 4; j++) acc[i][j] = (f32x4){0.f, 0.f, 0.f, 0.f};

    int srow = wid * 8 + (lane >> 3);
    int sxor = ((lane & 7) * 16) ^ (((lane >> 3) & 7) << 4);
    int swz = (lane & 7) << 4;
    const char* Xb = (const char*)X;
    const char* Wb = (const char*)Wt;
    char* AsB = (char*)As;
    char* BsB = (char*)Bs;

    for (int k0 = 0; k0 < Kd; k0 += 64) {
        for (int i = 0; i < 4; i++) {
            int row = i * 32 + srow;
            GLL16(Xb + ((size_t)(m0 + row) * Kd + k0) * 2 + sxor, AsB + i * 4096 + wid * 1024);
            GLL16(Wb + ((size_t)(n0 + row) * Kd + k0) * 2 + sxor, BsB + i * 4096 + wid * 1024);
        }
        __syncthreads();
        for (int kk = 0; kk < 2; kk++) {
            int cb = (((lane >> 4) * 16 + kk * 64) ^ swz);
            bf16x8 a[4], b[4];
            for (int mf = 0; mf < 4; mf++)
                a[mf] = *(const bf16x8*)(AsB + (wm * 64 + mf * 16 + (lane & 15)) * 128 + cb);
            for (int nf = 0; nf < 4; nf++)
                b[nf] = *(const bf16x8*)(BsB + (wn * 64 + nf * 16 + (lane & 15)) * 128 + cb);
            for (int mf = 0; mf < 4; mf++)
                for (int nf = 0; nf < 4; nf++) acc[mf][nf] = MFMA16(a[mf], b[nf], acc[mf][nf]);
        }
        __syncthreads();
    }

    int crow0 = m0 + wm * 64;
    int ccol0 = n0 + wn * 64;
    for (int nf = 0; nf < 4; nf++) {
        int col = ccol0 + nf * 16 + (lane & 15);
        float bv_;
        if (MODE == 3)
            bv_ = (col < 1024) ? bias0[col] : bias1[col - 1024];
        else
            bv_ = bias0[col];
        for (int mf = 0; mf < 4; mf++) {
            int rowb = crow0 + mf * 16 + (lane >> 4) * 4;
            for (int r = 0; r < 4; r++) {
                int row = rowb + r;
                float val = acc[mf][nf][r] + bv_;
                if (MODE == 2) {
                    ((float*)out0)[(size_t)row * 1024 + col] = val;
                } else {
                    int b = row >> 11, nq = row & 2047;
                    unsigned short bfv = f2bf(val);
                    if (MODE == 0) {
                        int h = col >> 6, d = col & 63;
                        ((unsigned short*)out0)[(((size_t)(b * H_ + h)) * NQ_ + nq) * 64 + d] = bfv;
                    } else {  // MODE 3
                        if (col < 1024) {
                            int h = col >> 6, d = col & 63;
                            ((unsigned short*)out0)[(((size_t)(b * H_ + h)) * NQ_ + nq) * 64 + d] = bfv;
                        } else {
                            int c = col - 1024;
                            int h = c >> 6, d = c & 63;
                            ((unsigned short*)out1)[(((size_t)(b * H_ + h)) * 64 + d) * NK_ + nq] = bfv;
                        }
                    }
                }
            }
        }
    }
}

// --------------------------------------------------------- flash attention
// Q,K: [B*H][2048][64] bf16 ; Vt: [B*H][64][2048] bf16
// out attended: [B*NQ][1024] bf16
// 8 waves x 32 q-rows (2 groups). K-frags hoisted to regs (read once, both
// groups). Per-group {exp, P-write, PV} phases sequenced so group-1 VALU can
// fill group-0's MFMA shadow. Union max + defer-max, l via ones-column MFMA.
__global__ __launch_bounds__(512, 4) void flash_attn(const unsigned short* __restrict__ Q,
                                                     const unsigned short* __restrict__ K,
                                                     const unsigned short* __restrict__ Vt,
                                                     unsigned short* __restrict__ attended) {
    __shared__ __align__(16) char smem[2][16384];        // [buf][ K 8KB | V 8KB ]
    __shared__ __align__(16) unsigned short Ps[8][2048]; // per-wave P, 4KB (2KB/group)
    int tid = threadIdx.x, lane = tid & 63, wid = tid >> 6;  // wid 0..7
    int g = lane >> 4;
    int q = lane & 15;

    int lin = blockIdx.y * 8 + blockIdx.x;       // 0..511
    int virt = (lin & 7) * 64 + (lin >> 3);      // bijective chunked map: 8 bh per XCD
    int bh = virt >> 3;
    int q0 = (virt & 7) * 256;
    const char* Qb = (const char*)(Q + (size_t)bh * NQ_ * 64);
    const char* Kb = (const char*)(K + (size_t)bh * NK_ * 64);
    const char* Vb = (const char*)(Vt + (size_t)bh * 64 * NK_);

    // Q fragments for both groups (B-operand of swapped QK^T)
    int qrow = q0 + wid * 32 + q;
    bf16x8 qf0[2], qf1[2];
    qf0[0] = *(const bf16x8*)(Qb + (size_t)qrow * 128 + g * 16);
    qf0[1] = *(const bf16x8*)(Qb + (size_t)qrow * 128 + g * 16 + 64);
    qf1[0] = *(const bf16x8*)(Qb + (size_t)(qrow + 16) * 128 + g * 16);
    qf1[1] = *(const bf16x8*)(Qb + (size_t)(qrow + 16) * 128 + g * 16 + 64);

    bf16x8 onesf;
#pragma unroll
    for (int i = 0; i < 8; i++) onesf[i] = (short)0x3f80;  // bf16 1.0

    f32x4 acc0[4], acc1[4];
    for (int i = 0; i < 4; i++) {
        acc0[i] = (f32x4){0.f, 0.f, 0.f, 0.f};
        acc1[i] = (f32x4){0.f, 0.f, 0.f, 0.f};
    }
    f32x4 accl0 = (f32x4){0.f, 0.f, 0.f, 0.f};
    f32x4 accl1 = (f32x4){0.f, 0.f, 0.f, 0.f};
    float mst = -3.0e38f;  // shared (union) running max across both groups

    int sxor = ((lane & 7) * 16) ^ (((lane >> 3) & 7) << 4);
    const char* kptr = Kb + (size_t)(wid * 8 + (lane >> 3)) * 128 + sxor;   // +8192/tile
    const char* vptr = Vb + (size_t)(wid * 8 + (lane >> 3)) * 4096 + sxor;  // +128/tile
    int cb0 = g * 16;
    int swz = (lane & 7) << 4;

    unsigned short* Pw = Ps[wid];
    uint32_t* P32 = (uint32_t*)Pw;
    int pwbase = q * 32 + ((g & 1) << 1);  // u32 index base for P writes
    int q7 = q & 7;
    // t-invariant P-write u32 indices and P-read byte offsets
    int pidx[4], prb[2];
#pragma unroll
    for (int nf = 0; nf < 4; nf++) pidx[nf] = pwbase + (((2 * nf + (g >> 1)) ^ q7) << 2);
#pragma unroll
    for (int kk = 0; kk < 2; kk++) prb[kk] = q * 128 + (((g + 4 * kk) ^ q7) << 4);

    GLL16(kptr, smem[0] + wid * 1024);
    GLL16(vptr, smem[0] + 8192 + wid * 1024);
    kptr += 8192;
    vptr += 128;
    __syncthreads();
    int cur = 0;

    for (int t = 0; t < NK_ / 64; ++t) {
        if (t < NK_ / 64 - 1) {
            GLL16(kptr, smem[cur ^ 1] + wid * 1024);
            GLL16(vptr, smem[cur ^ 1] + 8192 + wid * 1024);
            kptr += 8192;
            vptr += 128;
        }
        const char* Ksb = smem[cur];
        const char* Vsb = smem[cur] + 8192;

        // K fragments to regs once; QK^T for both groups
        bf16x8 kf[4][2];
#pragma unroll
        for (int nf = 0; nf < 4; nf++)
#pragma unroll
            for (int kk = 0; kk < 2; kk++)
                kf[nf][kk] = *(const bf16x8*)(Ksb + (nf * 16 + q) * 128 + ((cb0 + kk * 64) ^ swz));

        f32x4 s0[4], s1[4];
        __builtin_amdgcn_s_setprio(1);
#pragma unroll
        for (int nf = 0; nf < 4; nf++) {
            s0[nf] = (f32x4){0.f, 0.f, 0.f, 0.f};
            s0[nf] = MFMA16(kf[nf][0], qf0[0], s0[nf]);
            s0[nf] = MFMA16(kf[nf][1], qf0[1], s0[nf]);
        }
#pragma unroll
        for (int nf = 0; nf < 4; nf++) {
            s1[nf] = (f32x4){0.f, 0.f, 0.f, 0.f};
            s1[nf] = MFMA16(kf[nf][0], qf1[0], s1[nf]);
            s1[nf] = MFMA16(kf[nf][1], qf1[1], s1[nf]);
        }
        __builtin_amdgcn_s_setprio(0);

        // union max over both groups (max3-friendly tree) + 2 shuffles
#define VMAX4(a, b) (f32x4){fmaxf(a[0], b[0]), fmaxf(a[1], b[1]), fmaxf(a[2], b[2]), fmaxf(a[3], b[3])}
        f32x4 x0 = VMAX4(s0[0], s1[0]);
        f32x4 x1 = VMAX4(s0[1], s1[1]);
        f32x4 x2 = VMAX4(s0[2], s1[2]);
        f32x4 x3 = VMAX4(s0[3], s1[3]);
        x0 = VMAX4(x0, x2);
        x1 = VMAX4(x1, x3);
        x0 = VMAX4(x0, x1);
        float mloc = fmaxf(fmaxf(x0[0], x0[1]), fmaxf(x0[2], x0[3]));
        mloc = fmaxf(mloc, __shfl_xor(mloc, 16));
        mloc = fmaxf(mloc, __shfl_xor(mloc, 32));

        // defer-max: rescale only when max grew enough to matter (P <= 2^8)
        if (!__all(mloc - mst <= 44.36f)) {
            float mnew = fmaxf(mst, mloc);
            float alpha = __builtin_amdgcn_exp2f((mst - mnew) * C2);
            mst = mnew;
            float al[4];
#pragma unroll
            for (int r = 0; r < 4; r++) al[r] = __shfl(alpha, 4 * g + r);
#pragma unroll
            for (int r = 0; r < 4; r++) {
#pragma unroll
                for (int df = 0; df < 4; df++) {
                    acc0[df][r] *= al[r];
                    acc1[df][r] *= al[r];
                }
                accl0[r] *= al[r];
                accl1[r] *= al[r];
            }
        }
        float mc = mst * C2;

        // ---- group 0: exp + P-write + PV
#pragma unroll
        for (int nf = 0; nf < 4; nf++) {
            float e0 = __builtin_amdgcn_exp2f(s0[nf][0] * C2 - mc);
            float e1 = __builtin_amdgcn_exp2f(s0[nf][1] * C2 - mc);
            float e2 = __builtin_amdgcn_exp2f(s0[nf][2] * C2 - mc);
            float e3 = __builtin_amdgcn_exp2f(s0[nf][3] * C2 - mc);
            P32[pidx[nf]] = packbf2(e0, e1);
            P32[pidx[nf] + 1] = packbf2(e2, e3);
        }
        __builtin_amdgcn_s_setprio(1);
#pragma unroll
        for (int kk = 0; kk < 2; kk++) {
            bf16x8 ap0 = *(const bf16x8*)((const char*)Pw + prb[kk]);
#pragma unroll
            for (int df = 0; df < 4; df++) {
                bf16x8 bv = *(const bf16x8*)(Vsb + (df * 16 + q) * 128 + ((cb0 + kk * 64) ^ swz));
                acc0[df] = MFMA16(ap0, bv, acc0[df]);
            }
            accl0 = MFMA16(ap0, onesf, accl0);
        }
        __builtin_amdgcn_s_setprio(0);

        // ---- group 1: exp + P-write + PV (VALU here can fill PV0's shadow)
#pragma unroll
        for (int nf = 0; nf < 4; nf++) {
            float e0 = __builtin_amdgcn_exp2f(s1[nf][0] * C2 - mc);
            float e1 = __builtin_amdgcn_exp2f(s1[nf][1] * C2 - mc);
            float e2 = __builtin_amdgcn_exp2f(s1[nf][2] * C2 - mc);
            float e3 = __builtin_amdgcn_exp2f(s1[nf][3] * C2 - mc);
            P32[pidx[nf] + 512] = packbf2(e0, e1);
            P32[pidx[nf] + 513] = packbf2(e2, e3);
        }
        __builtin_amdgcn_s_setprio(1);
#pragma unroll
        for (int kk = 0; kk < 2; kk++) {
            bf16x8 ap1 = *(const bf16x8*)((const char*)Pw + 2048 + prb[kk]);
#pragma unroll
            for (int df = 0; df < 4; df++) {
                bf16x8 bv = *(const bf16x8*)(Vsb + (df * 16 + q) * 128 + ((cb0 + kk * 64) ^ swz));
                acc1[df] = MFMA16(ap1, bv, acc1[df]);
            }
            accl1 = MFMA16(ap1, onesf, accl1);
        }
        __builtin_amdgcn_s_setprio(0);
        __syncthreads();
        cur ^= 1;
    }

    int b = bh >> 4, h = bh & 15;
#pragma unroll
    for (int df = 0; df < 4; df++)
#pragma unroll
        for (int r = 0; r < 4; r++) {
            int row = q0 + wid * 32 + 4 * g + r;
            int col = h * 64 + df * 16 + q;
            attended[(size_t)(b * NQ_ + row) * CQ_ + col] = f2bf(acc0[df][r] / accl0[r]);
            attended[(size_t)(b * NQ_ + row + 16) * CQ_ + col] = f2bf(acc1[df][r] / accl1[r]);
        }
}

// ---------------------------------------------------------------- launcher
extern "C" void kernel_launch(void* const* d_in, const int* in_sizes, int n_in,
                              void* d_out, int out_size, void* d_ws, size_t ws_size,
                              hipStream_t stream) {
    const float* qt  = (const float*)d_in[0];
    const float* ct  = (const float*)d_in[1];
    const float* Wq  = (const float*)d_in[2];
    const float* bq  = (const float*)d_in[3];
    const float* Wk  = (const float*)d_in[4];
    const float* bk  = (const float*)d_in[5];
    const float* Wv  = (const float*)d_in[6];
    const float* bv  = (const float*)d_in[7];
    const float* Wo  = (const float*)d_in[8];
    const float* bo  = (const float*)d_in[9];
    const float* gq  = (const float*)d_in[10];
    const float* btq = (const float*)d_in[11];
    const float* gc  = (const float*)d_in[12];
    const float* btc = (const float*)d_in[13];

    char* ws = (char*)d_ws;
    unsigned short* xq   = (unsigned short*)(ws + 0);         // 16 MB (reused as attended)
    unsigned short* xc   = (unsigned short*)(ws + 16777216);  // 12 MB
    unsigned short* Wqt  = (unsigned short*)(ws + 29360128);  // 2 MB
    unsigned short* Wkvt = (unsigned short*)(ws + 31457280);  // 3 MB [2048][768]
    unsigned short* Wot  = (unsigned short*)(ws + 34603008);  // 2 MB
    unsigned short* Qb   = (unsigned short*)(ws + 36700160);  // 16 MB
    unsigned short* Kb   = (unsigned short*)(ws + 53477376);  // 16 MB
    unsigned short* Vtb  = (unsigned short*)(ws + 70254592);  // 16 MB  (total ~83 MB)

    ln_fused<<<16384, 256, 0, stream>>>(qt, ct, gq, btq, gc, btc, xq, xc);
    transpose_all<<<3584, dim3(32, 8), 0, stream>>>(Wq, Wk, Wv, Wo, Wqt, Wkvt, Wot);

    gemm_bt<0><<<dim3(8, 64), 256, 0, stream>>>(xq, Wqt, bq, nullptr, Qb, nullptr, 1024);
    gemm_bt<3><<<dim3(16, 64), 256, 0, stream>>>(xc, Wkvt, bk, bv, Kb, Vtb, 768);

    flash_attn<<<dim3(8, 64), 512, 0, stream>>>(Qb, Kb, Vtb, xq);

    gemm_bt<2><<<dim3(8, 64), 256, 0, stream>>>(xq, Wot, bo, nullptr, d_out, nullptr, 1024);
}